// Round 2
// baseline (483.924 us; speedup 1.0000x reference)
//
#include <hip/hip_runtime.h>

static constexpr int   B_   = 8;
static constexpr int   N_   = 2048;   // points in set 1 (rows)
static constexpr int   M_   = 2048;   // points in set 2 (cols)
static constexpr int   TPB  = 256;
static constexpr int   TILE = 32;                  // rows/cols owned per block
static constexpr int   NBLK = (B_ * N_) / TILE;    // 512 blocks per phase
static constexpr float EPS_ = 1e-9f;

// ws layout (floats):
//  [0]              x1f  : B*N*4   float4-packed xyz1
//  [B*N*4]          x2f  : B*M*4   float4-packed xyz2
//  [B*N*8]          satl : B*N
//  +B*N             satr : B*M
//  +B*M             scale: B*N
//  +B*N             wr   : B*M
//  +B*M             cost : B*N     per-row accumulated cost
// total = 13 * B*N floats = 832 KB

__global__ void __launch_bounds__(TPB)
emd_init(const float* __restrict__ xyz1, const float* __restrict__ xyz2,
         float* __restrict__ ws)
{
    const int idx = blockIdx.x * TPB + threadIdx.x;
    if (idx >= B_ * N_) return;
    float4* x1v = reinterpret_cast<float4*>(ws);
    float4* x2v = x1v + B_ * N_;
    float*  satl = ws + B_ * N_ * 8;
    float*  satr = satl + B_ * N_;
    float*  cost = satl + 4 * B_ * N_;
    x1v[idx] = make_float4(xyz1[idx*3], xyz1[idx*3+1], xyz1[idx*3+2], 0.f);
    x2v[idx] = make_float4(xyz2[idx*3], xyz2[idx*3+1], xyz2[idx*3+2], 0.f);
    satl[idx] = 1.f;
    satr[idx] = 1.f;
    cost[idx] = 0.f;
}

// PHASE 1: row pass  -> scale[row] = satl[row] / (rowsum + EPS)
// PHASE 2: col pass  -> rr, wr[col], satr[col] update
// PHASE 3: row pass  -> satl[row] update + cost[row] accumulation
template<int PHASE>
__global__ void __launch_bounds__(TPB)
emd_phase(float* __restrict__ ws, const float lvl2)
{
    float* x1f  = ws;
    float* x2f  = ws + B_ * N_ * 4;
    float* satl = ws + B_ * N_ * 8;
    float* satr = satl + B_ * N_;
    float* scal = satr + B_ * M_;
    float* wr   = scal + B_ * N_;
    float* cost = wr   + B_ * M_;

    __shared__ float4 pts[M_];        // 32 KB : streamed point set
    __shared__ float  aux[M_];        // 8 KB  : satr / scale / wr
    __shared__ float  red[64][33];    // 8.4 KB: chunk-partial reduction

    const int b    = blockIdx.x >> 6;     // 64 blocks per batch
    const int tile = blockIdx.x & 63;
    const int t    = threadIdx.x;
    const int g    = t & 3;               // owned-index group: 4 x 8
    const int c    = t >> 2;              // stream chunk: 64 x 32

    // stream source: phase 2 streams set-1 points, phases 1/3 stream set-2
    const float4* src  = (PHASE == 2)
        ? reinterpret_cast<const float4*>(x1f) + b * N_
        : reinterpret_cast<const float4*>(x2f) + b * M_;
    const float*  asrc = (PHASE == 1) ? (satr + b * M_)
                        : (PHASE == 2) ? (scal + b * N_)
                                       : (wr   + b * M_);
    for (int p = t; p < M_; p += TPB) { pts[p] = src[p]; aux[p] = asrc[p]; }

    // owned coords: phase 2 owns columns (set 2), phases 1/3 own rows (set 1)
    const float4* ownv = (PHASE == 2) ? reinterpret_cast<const float4*>(x2f)
                                      : reinterpret_cast<const float4*>(x1f);
    const int obase = b * N_ + tile * TILE + g * 8;
    float qx[8], qy[8], qz[8];
#pragma unroll
    for (int j = 0; j < 8; ++j) {
        float4 v = ownv[obase + j];
        qx[j] = v.x; qy[j] = v.y; qz[j] = v.z;
    }
    __syncthreads();

    float a1[8], ad[8];
#pragma unroll
    for (int j = 0; j < 8; ++j) { a1[j] = 0.f; ad[j] = 0.f; }
    for (int i = 0; i < 32; ++i) {
        const int l = c + (i << 6);
        const float4 p = pts[l];
        const float  s = aux[l];
#pragma unroll
        for (int j = 0; j < 8; ++j) {
            float dx = p.x - qx[j], dy = p.y - qy[j], dz = p.z - qz[j];
            float d2 = fmaf(dz, dz, fmaf(dy, dy, dx * dx));
            float e  = s * __builtin_amdgcn_exp2f(lvl2 * d2);
            a1[j] += e;
            if (PHASE == 3)
                ad[j] = fmaf(e, __builtin_amdgcn_sqrtf(d2), ad[j]);
        }
    }
#pragma unroll
    for (int j = 0; j < 8; ++j) red[c][g * 8 + j] = a1[j];
    __syncthreads();

    float s1 = 0.f;
    if (t < TILE)
        for (int cc = 0; cc < 64; ++cc) s1 += red[cc][t];

    if (PHASE == 3) {
        __syncthreads();
#pragma unroll
        for (int j = 0; j < 8; ++j) red[c][g * 8 + j] = ad[j];
        __syncthreads();
    }

    if (t < TILE) {
        const int idx = b * N_ + tile * TILE + t;
        if (PHASE == 1) {
            scal[idx] = satl[idx] / (s1 + EPS_);
        } else if (PHASE == 2) {
            const float sr  = satr[idx];
            const float w1s = sr * s1;                 // pre-clip column sum
            const float rr  = fminf(sr / (w1s + EPS_), 1.f);
            wr[idx]   = sr * rr;
            satr[idx] = fmaxf(sr - rr * w1s, 0.f);
        } else {
            float sd = 0.f;
            for (int cc = 0; cc < 64; ++cc) sd += red[cc][t];
            const float sc = scal[idx];
            satl[idx] = fmaxf(satl[idx] - sc * s1, 0.f);
            cost[idx] = fmaf(sc, sd, cost[idx]);
        }
    }
}

__global__ void __launch_bounds__(TPB)
emd_finish(const float* __restrict__ cost, float* __restrict__ out)
{
    const int b = blockIdx.x;
    const int t = threadIdx.x;
    float v = 0.f;
    for (int i = t; i < N_; i += TPB) v += cost[b * N_ + i];
#pragma unroll
    for (int k = 32; k >= 1; k >>= 1) v += __shfl_xor(v, k, 64);
    __shared__ float wsum[4];
    if ((t & 63) == 0) wsum[t >> 6] = v;
    __syncthreads();
    if (t == 0) out[b] = wsum[0] + wsum[1] + wsum[2] + wsum[3];
}

extern "C" void kernel_launch(void* const* d_in, const int* in_sizes, int n_in,
                              void* d_out, int out_size, void* d_ws, size_t ws_size,
                              hipStream_t stream)
{
    const float* xyz1 = (const float*)d_in[0];
    const float* xyz2 = (const float*)d_in[1];
    float* out = (float*)d_out;
    float* ws  = (float*)d_ws;

    emd_init<<<(B_ * N_) / TPB, TPB, 0, stream>>>(xyz1, xyz2, ws);

    static const float levels[11] = {
        -65536.f, -16384.f, -4096.f, -1024.f, -256.f,
        -64.f, -16.f, -4.f, -1.f, -0.25f, 0.f};
    const float LOG2E = 1.4426950408889634f;

    for (int lev = 0; lev < 11; ++lev) {
        const float lvl2 = levels[lev] * LOG2E;
        emd_phase<1><<<NBLK, TPB, 0, stream>>>(ws, lvl2);
        emd_phase<2><<<NBLK, TPB, 0, stream>>>(ws, lvl2);
        emd_phase<3><<<NBLK, TPB, 0, stream>>>(ws, lvl2);
    }

    float* cost = ws + B_ * N_ * 8 + 4 * B_ * N_;
    emd_finish<<<B_, TPB, 0, stream>>>(cost, out);
}

// Round 3
// 352.299 us; speedup vs baseline: 1.3736x; 1.3736x over previous
//
#include <hip/hip_runtime.h>
#include <math.h>

static constexpr int   B_   = 8;
static constexpr int   N_   = 2048;   // points per set
static constexpr int   TPB  = 256;
static constexpr int   TILE = 32;                  // rows/cols owned per block
static constexpr int   NBLK = (B_ * N_) / TILE;    // 512 blocks per pass
static constexpr int   BN   = B_ * N_;
static constexpr float EPS_ = 1e-9f;

// ws layout (floats):
//  x1f   [4*BN]  float4-packed xyz1 (w = |p|^2)
//  x2f   [4*BN]  float4-packed xyz2 (w = |p|^2)
//  satl  [BN]
//  satr  [BN]
//  scal  [BN]    raw scale (row factor)
//  lscal [BN]    log2(scale)
//  lsatr [BN]    log2(satr)
//  wr    [BN]    raw satr_old * r
//  lwr   [BN]    log2(wr)
//  cost  [BN]    per-row accumulated cost
#define WS_X1    (ws)
#define WS_X2    (ws + 4*BN)
#define WS_SATL  (ws + 8*BN)
#define WS_SATR  (ws + 9*BN)
#define WS_SCAL  (ws + 10*BN)
#define WS_LSCAL (ws + 11*BN)
#define WS_LSATR (ws + 12*BN)
#define WS_WR    (ws + 13*BN)
#define WS_LWR   (ws + 14*BN)
#define WS_COST  (ws + 15*BN)

__global__ void __launch_bounds__(TPB)
emd_init(const float* __restrict__ xyz1, const float* __restrict__ xyz2,
         float* __restrict__ ws)
{
    const int idx = blockIdx.x * TPB + threadIdx.x;
    if (idx >= BN) return;
    float x = xyz1[idx*3], y = xyz1[idx*3+1], z = xyz1[idx*3+2];
    reinterpret_cast<float4*>(WS_X1)[idx] =
        make_float4(x, y, z, fmaf(x,x, fmaf(y,y, z*z)));
    x = xyz2[idx*3]; y = xyz2[idx*3+1]; z = xyz2[idx*3+2];
    reinterpret_cast<float4*>(WS_X2)[idx] =
        make_float4(x, y, z, fmaf(x,x, fmaf(y,y, z*z)));
    WS_SATL[idx] = 1.f;
    WS_SATR[idx] = 1.f;
    WS_LSATR[idx] = 0.f;     // log2(1)
    WS_COST[idx] = 0.f;
}

// MODE 0: P1 (first level)   : stream x2 + lsatr, own rows   -> scal/lscal
// MODE 1: P2                 : stream x1 + lscal, own cols   -> satr/lsatr, wr/lwr
// MODE 2: P3(prev)+P1(cur)   : stream x2 + lwr + lsatr, own rows
//                              -> satl, cost, scal/lscal (next level)
// MODE 3: P3 final (lvl2=0)  : stream x2 + raw wr, own rows  -> cost
template<int MODE>
__global__ void __launch_bounds__(TPB)
emd_pass(float* __restrict__ ws, const float lvlA, const float lvlB)
{
    __shared__ float4 pts[N_];          // 32 KB
    __shared__ float  auxA[N_];         // 8 KB
    __shared__ float  auxB[N_];         // 8 KB (MODE 2 only)
    __shared__ float  red[64][33];      // 8.4 KB

    const int b    = blockIdx.x >> 6;
    const int tile = blockIdx.x & 63;
    const int t    = threadIdx.x;
    const int g    = t & 3;             // owned group: 4 x 8
    const int c    = t >> 2;            // stream chunk: 64 x 32

    // ---- stream sources ----
    const float4* src = (MODE == 1)
        ? reinterpret_cast<const float4*>(WS_X1) + b * N_
        : reinterpret_cast<const float4*>(WS_X2) + b * N_;
    const float* aA = (MODE == 0) ? (WS_LSATR + b * N_)
                     : (MODE == 1) ? (WS_LSCAL + b * N_)
                     : (MODE == 2) ? (WS_LWR   + b * N_)
                                   : (WS_WR    + b * N_);
    const float* aB = WS_LSATR + b * N_;   // MODE 2 only
    for (int p = t; p < N_; p += TPB) {
        pts[p]  = src[p];
        auxA[p] = aA[p];
        if (MODE == 2) auxB[p] = aB[p];
    }

    // ---- owned coefficients: d2 = p.w + cq + cx*px + cy*py + cz*pz ----
    const float4* ownv = (MODE == 1)
        ? reinterpret_cast<const float4*>(WS_X2)
        : reinterpret_cast<const float4*>(WS_X1);
    const int obase = b * N_ + tile * TILE + g * 8;
    float cx[8], cy[8], cz[8], cq[8];
#pragma unroll
    for (int j = 0; j < 8; ++j) {
        float4 v = ownv[obase + j];
        cx[j] = -2.f * v.x; cy[j] = -2.f * v.y; cz[j] = -2.f * v.z;
        cq[j] = v.w;
    }
    __syncthreads();

    float s1[8], s2[8], s3[8];
#pragma unroll
    for (int j = 0; j < 8; ++j) { s1[j] = 0.f; s2[j] = 0.f; s3[j] = 0.f; }

    for (int i = 0; i < 32; ++i) {
        const int l = c + (i << 6);
        const float4 p = pts[l];
        const float  wA = auxA[l];
        float wB;
        if (MODE == 2) wB = auxB[l];
#pragma unroll
        for (int j = 0; j < 8; ++j) {
            const float s0 = p.w + cq[j];
            const float d2 = fmaf(cx[j], p.x,
                             fmaf(cy[j], p.y,
                             fmaf(cz[j], p.z, s0)));
            if (MODE == 0 || MODE == 1) {
                s1[j] += __builtin_amdgcn_exp2f(fmaf(lvlB, d2, wA));
            } else if (MODE == 2) {
                const float sq = __builtin_amdgcn_sqrtf(fmaxf(d2, 0.f));
                const float eA = __builtin_amdgcn_exp2f(fmaf(lvlA, d2, wA));
                s1[j] += eA;                       // sum w (P3 part)
                s2[j]  = fmaf(eA, sq, s2[j]);      // sum w*d
                s3[j] += __builtin_amdgcn_exp2f(fmaf(lvlB, d2, wB)); // next rowsum
            } else { // MODE 3: lvl = 0 -> e = wr
                const float sq = __builtin_amdgcn_sqrtf(fmaxf(d2, 0.f));
                s2[j] = fmaf(wA, sq, s2[j]);       // sum wr*d
            }
        }
    }

    // ---- reductions (sequential rounds over red[64][33]) ----
    float rs1 = 0.f, rs2 = 0.f, rs3 = 0.f;
    if (MODE != 3) {
#pragma unroll
        for (int j = 0; j < 8; ++j) red[c][g * 8 + j] = s1[j];
        __syncthreads();
        if (t < TILE) for (int cc = 0; cc < 64; ++cc) rs1 += red[cc][t];
    }
    if (MODE >= 2) {
        if (MODE != 3) __syncthreads();
#pragma unroll
        for (int j = 0; j < 8; ++j) red[c][g * 8 + j] = s2[j];
        __syncthreads();
        if (t < TILE) for (int cc = 0; cc < 64; ++cc) rs2 += red[cc][t];
    }
    if (MODE == 2) {
        __syncthreads();
#pragma unroll
        for (int j = 0; j < 8; ++j) red[c][g * 8 + j] = s3[j];
        __syncthreads();
        if (t < TILE) for (int cc = 0; cc < 64; ++cc) rs3 += red[cc][t];
    }

    // ---- epilogue ----
    if (t < TILE) {
        const int idx = b * N_ + tile * TILE + t;
        if (MODE == 0) {
            const float sc = WS_SATL[idx] / (rs1 + EPS_);
            WS_SCAL[idx]  = sc;
            WS_LSCAL[idx] = __log2f(sc);
        } else if (MODE == 1) {
            const float sr  = WS_SATR[idx];
            const float w1s = sr * rs1;
            const float rr  = fminf(sr / (w1s + EPS_), 1.f);
            const float wrv = sr * rr;
            const float srn = fmaxf(sr - rr * w1s, 0.f);
            WS_WR[idx]    = wrv;
            WS_LWR[idx]   = __log2f(wrv);
            WS_SATR[idx]  = srn;
            WS_LSATR[idx] = __log2f(srn);
        } else if (MODE == 2) {
            const float scp  = WS_SCAL[idx];                  // prev level scale
            const float sln  = fmaxf(WS_SATL[idx] - scp * rs1, 0.f);
            WS_COST[idx]     = fmaf(scp, rs2, WS_COST[idx]);
            const float scn  = sln / (rs3 + EPS_);            // next level scale
            WS_SATL[idx]  = sln;
            WS_SCAL[idx]  = scn;
            WS_LSCAL[idx] = __log2f(scn);
        } else { // MODE 3
            WS_COST[idx] = fmaf(WS_SCAL[idx], rs2, WS_COST[idx]);
        }
    }
}

__global__ void __launch_bounds__(TPB)
emd_finish(const float* __restrict__ cost, float* __restrict__ out)
{
    const int b = blockIdx.x;
    const int t = threadIdx.x;
    float v = 0.f;
    for (int i = t; i < N_; i += TPB) v += cost[b * N_ + i];
#pragma unroll
    for (int k = 32; k >= 1; k >>= 1) v += __shfl_xor(v, k, 64);
    __shared__ float wsum[4];
    if ((t & 63) == 0) wsum[t >> 6] = v;
    __syncthreads();
    if (t == 0) out[b] = wsum[0] + wsum[1] + wsum[2] + wsum[3];
}

extern "C" void kernel_launch(void* const* d_in, const int* in_sizes, int n_in,
                              void* d_out, int out_size, void* d_ws, size_t ws_size,
                              hipStream_t stream)
{
    const float* xyz1 = (const float*)d_in[0];
    const float* xyz2 = (const float*)d_in[1];
    float* out = (float*)d_out;
    float* ws  = (float*)d_ws;

    emd_init<<<BN / TPB, TPB, 0, stream>>>(xyz1, xyz2, ws);

    static const float levels[11] = {
        -65536.f, -16384.f, -4096.f, -1024.f, -256.f,
        -64.f, -16.f, -4.f, -1.f, -0.25f, 0.f};
    const float LOG2E = 1.4426950408889634f;

    // level 0: P1, P2
    emd_pass<0><<<NBLK, TPB, 0, stream>>>(ws, 0.f, levels[0] * LOG2E);
    emd_pass<1><<<NBLK, TPB, 0, stream>>>(ws, 0.f, levels[0] * LOG2E);
    // levels 1..10: merged P3(prev)+P1(cur), then P2(cur)
    for (int lev = 1; lev < 11; ++lev) {
        emd_pass<2><<<NBLK, TPB, 0, stream>>>(ws, levels[lev-1] * LOG2E,
                                                  levels[lev]   * LOG2E);
        emd_pass<1><<<NBLK, TPB, 0, stream>>>(ws, 0.f, levels[lev] * LOG2E);
    }
    // final P3 (level 10, lvl2 = 0)
    emd_pass<3><<<NBLK, TPB, 0, stream>>>(ws, 0.f, 0.f);

    emd_finish<<<B_, TPB, 0, stream>>>(WS_COST, out);
}